// Round 15
// baseline (173.354 us; speedup 1.0000x reference)
//
#include <hip/hip_runtime.h>
#include <hip/hip_bf16.h>
#include <hip/hip_fp16.h>

// Problem constants
#define BB 8
#define CIN 128
#define HH 48
#define WW 48
#define HW 2304          // 48*48
#define KK 9
#define COUT 256
#define KC 1152          // K*CIN
#define MM 18432         // B*HW
#define MT 16            // M-tile rows per block
#define SFP 136          // feats LDS row stride in elements (16B-aligned)

// Barrier that waits only on LDS ops (ds_write visibility), leaving global
// loads in flight across the barrier.
#define LIGHT_BARRIER() asm volatile("s_waitcnt lgkmcnt(0)\n\ts_barrier" ::: "memory")

typedef short bf16x8_t __attribute__((ext_vector_type(8)));
typedef float f32x4_t  __attribute__((ext_vector_type(4)));

static __device__ __forceinline__ float b2f(short u) {
    union { unsigned int i; float f; } c;
    c.i = ((unsigned int)(unsigned short)u) << 16;
    return c.f;
}

// ---------------------------------------------------------------------------
// PREP kernel (R16 version, kept): transpose (0..575), pack_wu (576..719),
// params MLP in 3 groups of 9 (720..1295).
// ---------------------------------------------------------------------------
__global__ __launch_bounds__(256) void prep_kernel(
    const float* __restrict__ x, __hip_bfloat16* __restrict__ xT,
    const float* __restrict__ Wu, bf16x8_t* __restrict__ Bp,
    const float* __restrict__ W1, const float* __restrict__ b1,
    const float* __restrict__ W2, const float* __restrict__ b2,
    float* __restrict__ means, float* __restrict__ sigmas, int* __restrict__ fls)
{
    __shared__ double s_par[4][27];               // MLP group stash (864 B)
    int bid = blockIdx.x;
    int t = threadIdx.x;

    if (bid < 576) {
        __shared__ float tile[64][65];
        int ij0 = (bid % 36) * 64;
        int c0  = ((bid / 36) % 2) * 64;
        int b   = bid / 72;
        int ijl = t & 63, cl = t >> 6;
        #pragma unroll
        for (int i = 0; i < 16; i++) {
            int cc = i*4 + cl;
            tile[cc][ijl] = x[(size_t)(b*CIN + c0 + cc) * HW + ij0 + ijl];
        }
        __syncthreads();
        int cl2 = t & 63, ijl2 = t >> 6;
        #pragma unroll
        for (int i = 0; i < 16; i++) {
            int ij = i*4 + ijl2;
            xT[(size_t)(b*HW + ij0 + ij) * CIN + c0 + cl2] = __float2bfloat16(tile[cl2][ij]);
        }
    } else if (bid < 720) {
        int idx = (bid - 576) * 256 + t;          // 0 .. 36863
        int lane = idx & 63;
        int rest = idx >> 6;                      // 0 .. 575
        int ksub = rest % 36, tile16 = rest / 36;
        const float* src = Wu + (size_t)(tile16*16 + (lane & 15)) * KC
                              + ksub*32 + (lane >> 4)*8;
        union { bf16x8_t v; __hip_bfloat16 h[8]; } o;
        #pragma unroll
        for (int j = 0; j < 8; j++) o.h[j] = __float2bfloat16(src[j]);
        Bp[idx] = o.v;
    } else {
        int wave = t >> 6, lane = t & 63;
        int p = (bid - 720) * 4 + wave;           // 0..2303
        int iy = p / WW, ix = p % WW;
        float ryf = (float)iy / 47.0f;
        float rxf = (float)ix / 47.0f;
        double ry = (double)ryf, rx = (double)rxf;

        double h[8];
        #pragma unroll
        for (int jj = 0; jj < 8; jj++) {
            int j = lane*8 + jj;
            double v = ry * (double)W1[j*2+0] + rx * (double)W1[j*2+1] + (double)b1[j];
            h[jj] = v > 0.0 ? v : 0.0;
        }
        for (int g = 0; g < 3; g++) {
            double par[9];
            #pragma unroll
            for (int oo = 0; oo < 9; oo++) {
                int o = g*9 + oo;
                const float4* w4 = (const float4*)(W2 + (size_t)o*512 + lane*8);
                float4 wa = w4[0], wb = w4[1];
                double s = (double)wa.x*h[0] + (double)wa.y*h[1]
                         + (double)wa.z*h[2] + (double)wa.w*h[3]
                         + (double)wb.x*h[4] + (double)wb.y*h[5]
                         + (double)wb.z*h[6] + (double)wb.w*h[7];
                par[oo] = s;
            }
            #pragma unroll
            for (int oo = 0; oo < 9; oo++) {
                #pragma unroll
                for (int d = 1; d < 64; d <<= 1)
                    par[oo] += __shfl_xor(par[oo], d, 64);
            }
            if (lane == 0) {
                #pragma unroll
                for (int oo = 0; oo < 9; oo++)
                    s_par[wave][g*9 + oo] = par[oo] + (double)b2[g*9 + oo];
            }
        }
        __syncthreads();
        if (lane < KK) {
            int k = lane;
            double scy = ry * 0.9999 + 5e-05;
            double scx = rx * 0.9999 + 5e-05;
            double midy = log(scy / (1.0 - scy));
            double midx = log(scx / (1.0 - scx));
            double zy = midy + 0.1 * s_par[wave][2*k+0];
            double zx = midx + 0.1 * s_par[wave][2*k+1];
            double my = 47.0 / (1.0 + exp(-zy));
            double mx = 47.0 / (1.0 + exp(-zx));
            double sr = s_par[wave][18 + k] + 2.0;
            double sp = (sr > 0.0 ? sr : 0.0) + log1p(exp(-fabs(sr)));
            double sg = (sp + 0.05) * 48.0 * 0.05;
            means[(p*KK + k)*2 + 0] = (float)my;
            means[(p*KK + k)*2 + 1] = (float)mx;
            sigmas[p*KK + k] = (float)sg;
            fls[(p*KK + k)*2 + 0] = (int)floor(my);
            fls[(p*KK + k)*2 + 1] = (int)floor(mx);
        }
    }
}

// ---------------------------------------------------------------------------
// FUSED gather + GEMM (R17): R14's two-phase structure but s_feat shrunk to
// 5 slots (21.8KB; block total 26.4KB) by splitting the k-loop into 2 rounds:
//   gather(0-4)->slots0-4 | bar | mfma(0-4) | bar | gather(5-8)->slots0-3
//   | bar | mfma(5-8).
// LDS 44KB->26.4KB lifts the residency cap 3->6 blocks/CU (12->24 waves/CU):
// R14's counters (VALU 28%, waves ~90% stalled, 3 waves/SIMD) say the kernel
// is latency-bound with too little TLP; doubling resident waves is the lever.
// Chunk-5 taps prefetch before the mid barriers (register-destined, ride
// across). Same per-k math order -> bit-identical output.
// ---------------------------------------------------------------------------
__global__ __launch_bounds__(256, 6) void fused_kernel(
    const float* __restrict__ means, const float* __restrict__ sigmas,
    const int* __restrict__ fls, const int* __restrict__ gints,
    const int* __restrict__ roff, const short* __restrict__ xT,
    const bf16x8_t* __restrict__ Bp, const float* __restrict__ bu,
    float* __restrict__ out)
{
    __shared__ unsigned int s_tap[KK*MT*8];              // 4608 B
    __shared__ __align__(16) short s_feat[5][MT*SFP];    // 21760 B

    int t = threadIdx.x;
    int b   = blockIdx.x & 7;
    int grp = blockIdx.x >> 3;          // 0..143 within batch
    int ij0 = grp * MT;
    int m0  = b * HW + ij0;

    if (t < KK*MT) {                    // 144 threads
        int p = t;
        int k = p >> 4, row = p & 15;
        int ij = ij0 + row;
        int bij = m0 + row;
        int fy = fls[(ij*KK + k)*2 + 0];
        int fx = fls[(ij*KK + k)*2 + 1];
        float my = means[(ij*KK + k)*2 + 0];
        float mx = means[(ij*KK + k)*2 + 1];
        float sg = sigmas[ij*KK + k];
        int lins[8]; float ws[8];
        #pragma unroll
        for (int v = 0; v < 8; v++) {
            int iy, ix;
            if (v < 4) {
                iy = fy + (v >> 1); ix = fx + (v & 1);
            } else if (v < 6) {
                int base = ((bij*KK + k)*2 + (v - 4)) * 2;
                iy = gints[base]; ix = gints[base + 1];
            } else {
                int base = ((bij*KK + k)*2 + (v - 6)) * 2;
                iy = fy + roff[base] - 6; ix = fx + roff[base + 1] - 6;
            }
            iy = ((iy % HH) + HH) % HH;
            ix = ((ix % WW) + WW) % WW;
            lins[v] = iy * WW + ix;
            float dy = ((float)iy - my) / sg;
            float dx = ((float)ix - mx) / sg;
            ws[v] = expf(-0.5f * (dy*dy + dx*dx));
        }
        #pragma unroll
        for (int v = 1; v < 8; v++) {
            bool dup = false;
            #pragma unroll
            for (int u = 0; u < 8; u++) if (u < v) dup = dup || (lins[u] == lins[v]);
            if (dup) ws[v] = 0.0f;
        }
        float sum = 0.0f;
        #pragma unroll
        for (int v = 0; v < 8; v++) sum += ws[v];
        float inv = 1.0f / sum;
        #pragma unroll
        for (int v = 0; v < 8; v++) {
            unsigned short hb = __half_as_ushort(__float2half(ws[v] * inv));
            s_tap[p*8+v] = ((unsigned int)lins[v] << 16) | (unsigned int)hb;
        }
    }
    LIGHT_BARRIER();

    const short* xb = xT + (size_t)b * (HW * CIN);
    int lane = t & 63, wave = t >> 6;             // wave 0..3
    int grow = t >> 4, gc0 = (t & 15) << 3;       // gather: row (0..15), 8-ch base
    int arow = lane & 15, aq = lane >> 4;         // MFMA A/C lane decomposition

    f32x4_t acc[4] = {};                          // 4 col-tiles of 16
    bf16x8_t tap[8];
    float    wgt[8];
    // prologue: taps for chunk 0
    {
        const unsigned int* tp = &s_tap[(0*MT + grow)*8];
        #pragma unroll
        for (int v = 0; v < 8; v++) {
            unsigned int e = tp[v];
            wgt[v] = __half2float(__ushort_as_half((unsigned short)(e & 0xffffu)));
            tap[v] = *(const bf16x8_t*)(xb + (size_t)(e >> 16) * CIN + gc0);
        }
    }

    // ---- round A: gather chunks 0..4 -> slots 0..4
    for (int k = 0; k < 5; k++) {
        float a0[8];
        #pragma unroll
        for (int j = 0; j < 8; j++) a0[j] = 0.0f;
        #pragma unroll
        for (int v = 0; v < 8; v++) {
            float w = wgt[v]; bf16x8_t d8 = tap[v];
            #pragma unroll
            for (int j = 0; j < 8; j++) a0[j] += w * b2f(d8[j]);
        }
        // prefetch taps for chunk k+1 (k=4 loads chunk 5: rides across the
        // two barriers below, consumed in round B)
        {
            const unsigned int* tp = &s_tap[((k+1)*MT + grow)*8];
            #pragma unroll
            for (int v = 0; v < 8; v++) {
                unsigned int e = tp[v];
                wgt[v] = __half2float(__ushort_as_half((unsigned short)(e & 0xffffu)));
                tap[v] = *(const bf16x8_t*)(xb + (size_t)(e >> 16) * CIN + gc0);
            }
        }
        union { bf16x8_t v8; __hip_bfloat16 hh[8]; } o;
        #pragma unroll
        for (int j = 0; j < 8; j++) o.hh[j] = __float2bfloat16(a0[j]);
        *(bf16x8_t*)(&s_feat[k][grow*SFP + gc0]) = o.v8;
    }
    LIGHT_BARRIER();
    // ---- MFMA chunks 0..4 (slots 0..4)
    for (int k = 0; k < 5; k++) {
        bf16x8_t Bf[16];
        {
            int base = (wave*4*36 + k*4)*64 + lane;
            #pragma unroll
            for (int tl = 0; tl < 4; tl++)
                #pragma unroll
                for (int s4 = 0; s4 < 4; s4++)
                    Bf[tl*4 + s4] = Bp[base + (tl*36 + s4)*64];
        }
        const short* fb = s_feat[k];
        bf16x8_t av[4];
        #pragma unroll
        for (int s4 = 0; s4 < 4; s4++)
            av[s4] = *(const bf16x8_t*)(fb + arow*SFP + s4*32 + aq*8);
        #pragma unroll
        for (int tl = 0; tl < 4; tl++)
            #pragma unroll
            for (int s4 = 0; s4 < 4; s4++)
                acc[tl] = __builtin_amdgcn_mfma_f32_16x16x32_bf16(av[s4], Bf[tl*4 + s4], acc[tl], 0, 0, 0);
    }
    LIGHT_BARRIER();   // all waves done reading slots 0..3 before reuse
    // ---- round B: gather chunks 5..8 -> slots 0..3
    for (int k = 5; k < KK; k++) {
        float a0[8];
        #pragma unroll
        for (int j = 0; j < 8; j++) a0[j] = 0.0f;
        #pragma unroll
        for (int v = 0; v < 8; v++) {
            float w = wgt[v]; bf16x8_t d8 = tap[v];
            #pragma unroll
            for (int j = 0; j < 8; j++) a0[j] += w * b2f(d8[j]);
        }
        if (k < KK - 1) {
            const unsigned int* tp = &s_tap[((k+1)*MT + grow)*8];
            #pragma unroll
            for (int v = 0; v < 8; v++) {
                unsigned int e = tp[v];
                wgt[v] = __half2float(__ushort_as_half((unsigned short)(e & 0xffffu)));
                tap[v] = *(const bf16x8_t*)(xb + (size_t)(e >> 16) * CIN + gc0);
            }
        }
        union { bf16x8_t v8; __hip_bfloat16 hh[8]; } o;
        #pragma unroll
        for (int j = 0; j < 8; j++) o.hh[j] = __float2bfloat16(a0[j]);
        *(bf16x8_t*)(&s_feat[k-5][grow*SFP + gc0]) = o.v8;
    }
    LIGHT_BARRIER();
    // ---- MFMA chunks 5..8 (slots 0..3)
    for (int k = 5; k < KK; k++) {
        bf16x8_t Bf[16];
        {
            int base = (wave*4*36 + k*4)*64 + lane;
            #pragma unroll
            for (int tl = 0; tl < 4; tl++)
                #pragma unroll
                for (int s4 = 0; s4 < 4; s4++)
                    Bf[tl*4 + s4] = Bp[base + (tl*36 + s4)*64];
        }
        const short* fb = s_feat[k-5];
        bf16x8_t av[4];
        #pragma unroll
        for (int s4 = 0; s4 < 4; s4++)
            av[s4] = *(const bf16x8_t*)(fb + arow*SFP + s4*32 + aq*8);
        #pragma unroll
        for (int tl = 0; tl < 4; tl++)
            #pragma unroll
            for (int s4 = 0; s4 < 4; s4++)
                acc[tl] = __builtin_amdgcn_mfma_f32_16x16x32_bf16(av[s4], Bf[tl*4 + s4], acc[tl], 0, 0, 0);
    }

    // ---- epilogue
    #pragma unroll
    for (int tl = 0; tl < 4; tl++) {
        int n = (wave*4 + tl)*16 + arow;
        float bv = bu[n];
        f32x4_t vv;
        vv[0] = acc[tl][0] + bv;
        vv[1] = acc[tl][1] + bv;
        vv[2] = acc[tl][2] + bv;
        vv[3] = acc[tl][3] + bv;
        *(f32x4_t*)(out + ((size_t)b * COUT + n) * HW + ij0 + aq*4) = vv;
    }
}

// ---------------------------------------------------------------------------
extern "C" void kernel_launch(void* const* d_in, const int* in_sizes, int n_in,
                              void* d_out, int out_size, void* d_ws, size_t ws_size,
                              hipStream_t stream)
{
    const float* x   = (const float*)d_in[0];
    const float* W1  = (const float*)d_in[1];
    const float* b1  = (const float*)d_in[2];
    const float* W2  = (const float*)d_in[3];
    const float* b2  = (const float*)d_in[4];
    const float* Wu  = (const float*)d_in[5];
    const float* bu  = (const float*)d_in[6];
    const int* gints = (const int*)d_in[7];
    const int* roff  = (const int*)d_in[8];
    float* out = (float*)d_out;

    char* ws = (char*)d_ws;
    float* ws_means  = (float*)(ws + 0);                    // 2304*18 fp32
    float* ws_sigma  = (float*)(ws + 165888);               // 2304*9  fp32
    int*   ws_fl     = (int*  )(ws + 248832);               // 2304*18 int
    short* ws_xT     = (short*)(ws + 414720);               // 8*2304*128 bf16
    bf16x8_t* ws_bp  = (bf16x8_t*)(ws + 5133312);           // packed Wu bf16

    prep_kernel<<<1296, 256, 0, stream>>>(x, (__hip_bfloat16*)ws_xT, Wu, ws_bp,
                                          W1, b1, W2, b2,
                                          ws_means, ws_sigma, ws_fl);
    fused_kernel<<<MM/MT, 256, 0, stream>>>(ws_means, ws_sigma, ws_fl, gints, roff,
                                            ws_xT, ws_bp, bu, out);
}

// Round 17
// 144.788 us; speedup vs baseline: 1.1973x; 1.1973x over previous
//
#include <hip/hip_runtime.h>
#include <hip/hip_bf16.h>
#include <hip/hip_fp16.h>

// Problem constants
#define BB 8
#define CIN 128
#define HH 48
#define WW 48
#define HW 2304          // 48*48
#define KK 9
#define COUT 256
#define KC 1152          // K*CIN
#define MM 18432         // B*HW
#define MT 16            // M-tile rows per block
#define SFP 136          // feats LDS row stride in elements (16B-aligned)

// Barrier that waits only on LDS ops (ds_write visibility), leaving global
// loads in flight across the barrier.
#define LIGHT_BARRIER() asm volatile("s_waitcnt lgkmcnt(0)\n\ts_barrier" ::: "memory")

typedef short bf16x8_t __attribute__((ext_vector_type(8)));
typedef float f32x4_t  __attribute__((ext_vector_type(4)));

static __device__ __forceinline__ float b2f(short u) {
    union { unsigned int i; float f; } c;
    c.i = ((unsigned int)(unsigned short)u) << 16;
    return c.f;
}

// ---------------------------------------------------------------------------
// PREP kernel (R16 version, kept): transpose (0..575), pack_wu (576..719),
// params MLP in 3 groups of 9 (720..1295).
// ---------------------------------------------------------------------------
__global__ __launch_bounds__(256) void prep_kernel(
    const float* __restrict__ x, __hip_bfloat16* __restrict__ xT,
    const float* __restrict__ Wu, bf16x8_t* __restrict__ Bp,
    const float* __restrict__ W1, const float* __restrict__ b1,
    const float* __restrict__ W2, const float* __restrict__ b2,
    float* __restrict__ means, float* __restrict__ sigmas, int* __restrict__ fls)
{
    __shared__ double s_par[4][27];               // MLP group stash (864 B)
    int bid = blockIdx.x;
    int t = threadIdx.x;

    if (bid < 576) {
        __shared__ float tile[64][65];
        int ij0 = (bid % 36) * 64;
        int c0  = ((bid / 36) % 2) * 64;
        int b   = bid / 72;
        int ijl = t & 63, cl = t >> 6;
        #pragma unroll
        for (int i = 0; i < 16; i++) {
            int cc = i*4 + cl;
            tile[cc][ijl] = x[(size_t)(b*CIN + c0 + cc) * HW + ij0 + ijl];
        }
        __syncthreads();
        int cl2 = t & 63, ijl2 = t >> 6;
        #pragma unroll
        for (int i = 0; i < 16; i++) {
            int ij = i*4 + ijl2;
            xT[(size_t)(b*HW + ij0 + ij) * CIN + c0 + cl2] = __float2bfloat16(tile[cl2][ij]);
        }
    } else if (bid < 720) {
        int idx = (bid - 576) * 256 + t;          // 0 .. 36863
        int lane = idx & 63;
        int rest = idx >> 6;                      // 0 .. 575
        int ksub = rest % 36, tile16 = rest / 36;
        const float* src = Wu + (size_t)(tile16*16 + (lane & 15)) * KC
                              + ksub*32 + (lane >> 4)*8;
        union { bf16x8_t v; __hip_bfloat16 h[8]; } o;
        #pragma unroll
        for (int j = 0; j < 8; j++) o.h[j] = __float2bfloat16(src[j]);
        Bp[idx] = o.v;
    } else {
        int wave = t >> 6, lane = t & 63;
        int p = (bid - 720) * 4 + wave;           // 0..2303
        int iy = p / WW, ix = p % WW;
        float ryf = (float)iy / 47.0f;
        float rxf = (float)ix / 47.0f;
        double ry = (double)ryf, rx = (double)rxf;

        double h[8];
        #pragma unroll
        for (int jj = 0; jj < 8; jj++) {
            int j = lane*8 + jj;
            double v = ry * (double)W1[j*2+0] + rx * (double)W1[j*2+1] + (double)b1[j];
            h[jj] = v > 0.0 ? v : 0.0;
        }
        for (int g = 0; g < 3; g++) {
            double par[9];
            #pragma unroll
            for (int oo = 0; oo < 9; oo++) {
                int o = g*9 + oo;
                const float4* w4 = (const float4*)(W2 + (size_t)o*512 + lane*8);
                float4 wa = w4[0], wb = w4[1];
                double s = (double)wa.x*h[0] + (double)wa.y*h[1]
                         + (double)wa.z*h[2] + (double)wa.w*h[3]
                         + (double)wb.x*h[4] + (double)wb.y*h[5]
                         + (double)wb.z*h[6] + (double)wb.w*h[7];
                par[oo] = s;
            }
            #pragma unroll
            for (int oo = 0; oo < 9; oo++) {
                #pragma unroll
                for (int d = 1; d < 64; d <<= 1)
                    par[oo] += __shfl_xor(par[oo], d, 64);
            }
            if (lane == 0) {
                #pragma unroll
                for (int oo = 0; oo < 9; oo++)
                    s_par[wave][g*9 + oo] = par[oo] + (double)b2[g*9 + oo];
            }
        }
        __syncthreads();
        if (lane < KK) {
            int k = lane;
            double scy = ry * 0.9999 + 5e-05;
            double scx = rx * 0.9999 + 5e-05;
            double midy = log(scy / (1.0 - scy));
            double midx = log(scx / (1.0 - scx));
            double zy = midy + 0.1 * s_par[wave][2*k+0];
            double zx = midx + 0.1 * s_par[wave][2*k+1];
            double my = 47.0 / (1.0 + exp(-zy));
            double mx = 47.0 / (1.0 + exp(-zx));
            double sr = s_par[wave][18 + k] + 2.0;
            double sp = (sr > 0.0 ? sr : 0.0) + log1p(exp(-fabs(sr)));
            double sg = (sp + 0.05) * 48.0 * 0.05;
            means[(p*KK + k)*2 + 0] = (float)my;
            means[(p*KK + k)*2 + 1] = (float)mx;
            sigmas[p*KK + k] = (float)sg;
            fls[(p*KK + k)*2 + 0] = (int)floor(my);
            fls[(p*KK + k)*2 + 1] = (int)floor(mx);
        }
    }
}

// ---------------------------------------------------------------------------
// FUSED gather + GEMM (R18): R17's 5-slot / two-round structure with the
// spill fixed: __launch_bounds__(256,4) (VGPR cap 128 — the config family
// where this body measured 60-84 VGPR, zero scratch). R17's (256,6) capped
// VGPR at ~85 -> compiler spilled Bf/tap to scratch (WRITE_SIZE 18->113MB,
// 2x slower). Occupancy: LDS 26.6KB -> 6 blocks/CU; bound allows 16 waves/CU
// (4/SIMD) — +33% over R14's 12 — WITHOUT spilling.
// ---------------------------------------------------------------------------
__global__ __launch_bounds__(256, 4) void fused_kernel(
    const float* __restrict__ means, const float* __restrict__ sigmas,
    const int* __restrict__ fls, const int* __restrict__ gints,
    const int* __restrict__ roff, const short* __restrict__ xT,
    const bf16x8_t* __restrict__ Bp, const float* __restrict__ bu,
    float* __restrict__ out)
{
    __shared__ unsigned int s_tap[KK*MT*8];              // 4608 B
    __shared__ __align__(16) short s_feat[5][MT*SFP];    // 21760 B

    int t = threadIdx.x;
    int b   = blockIdx.x & 7;
    int grp = blockIdx.x >> 3;          // 0..143 within batch
    int ij0 = grp * MT;
    int m0  = b * HW + ij0;

    if (t < KK*MT) {                    // 144 threads
        int p = t;
        int k = p >> 4, row = p & 15;
        int ij = ij0 + row;
        int bij = m0 + row;
        int fy = fls[(ij*KK + k)*2 + 0];
        int fx = fls[(ij*KK + k)*2 + 1];
        float my = means[(ij*KK + k)*2 + 0];
        float mx = means[(ij*KK + k)*2 + 1];
        float sg = sigmas[ij*KK + k];
        int lins[8]; float ws[8];
        #pragma unroll
        for (int v = 0; v < 8; v++) {
            int iy, ix;
            if (v < 4) {
                iy = fy + (v >> 1); ix = fx + (v & 1);
            } else if (v < 6) {
                int base = ((bij*KK + k)*2 + (v - 4)) * 2;
                iy = gints[base]; ix = gints[base + 1];
            } else {
                int base = ((bij*KK + k)*2 + (v - 6)) * 2;
                iy = fy + roff[base] - 6; ix = fx + roff[base + 1] - 6;
            }
            iy = ((iy % HH) + HH) % HH;
            ix = ((ix % WW) + WW) % WW;
            lins[v] = iy * WW + ix;
            float dy = ((float)iy - my) / sg;
            float dx = ((float)ix - mx) / sg;
            ws[v] = expf(-0.5f * (dy*dy + dx*dx));
        }
        #pragma unroll
        for (int v = 1; v < 8; v++) {
            bool dup = false;
            #pragma unroll
            for (int u = 0; u < 8; u++) if (u < v) dup = dup || (lins[u] == lins[v]);
            if (dup) ws[v] = 0.0f;
        }
        float sum = 0.0f;
        #pragma unroll
        for (int v = 0; v < 8; v++) sum += ws[v];
        float inv = 1.0f / sum;
        #pragma unroll
        for (int v = 0; v < 8; v++) {
            unsigned short hb = __half_as_ushort(__float2half(ws[v] * inv));
            s_tap[p*8+v] = ((unsigned int)lins[v] << 16) | (unsigned int)hb;
        }
    }
    LIGHT_BARRIER();

    const short* xb = xT + (size_t)b * (HW * CIN);
    int lane = t & 63, wave = t >> 6;             // wave 0..3
    int grow = t >> 4, gc0 = (t & 15) << 3;       // gather: row (0..15), 8-ch base
    int arow = lane & 15, aq = lane >> 4;         // MFMA A/C lane decomposition

    f32x4_t acc[4] = {};                          // 4 col-tiles of 16
    bf16x8_t tap[8];
    float    wgt[8];
    // prologue: taps for chunk 0
    {
        const unsigned int* tp = &s_tap[(0*MT + grow)*8];
        #pragma unroll
        for (int v = 0; v < 8; v++) {
            unsigned int e = tp[v];
            wgt[v] = __half2float(__ushort_as_half((unsigned short)(e & 0xffffu)));
            tap[v] = *(const bf16x8_t*)(xb + (size_t)(e >> 16) * CIN + gc0);
        }
    }

    // ---- round A: gather chunks 0..4 -> slots 0..4
    for (int k = 0; k < 5; k++) {
        float a0[8];
        #pragma unroll
        for (int j = 0; j < 8; j++) a0[j] = 0.0f;
        #pragma unroll
        for (int v = 0; v < 8; v++) {
            float w = wgt[v]; bf16x8_t d8 = tap[v];
            #pragma unroll
            for (int j = 0; j < 8; j++) a0[j] += w * b2f(d8[j]);
        }
        // prefetch taps for chunk k+1 (k=4 loads chunk 5: rides across the
        // two barriers below, consumed in round B)
        {
            const unsigned int* tp = &s_tap[((k+1)*MT + grow)*8];
            #pragma unroll
            for (int v = 0; v < 8; v++) {
                unsigned int e = tp[v];
                wgt[v] = __half2float(__ushort_as_half((unsigned short)(e & 0xffffu)));
                tap[v] = *(const bf16x8_t*)(xb + (size_t)(e >> 16) * CIN + gc0);
            }
        }
        union { bf16x8_t v8; __hip_bfloat16 hh[8]; } o;
        #pragma unroll
        for (int j = 0; j < 8; j++) o.hh[j] = __float2bfloat16(a0[j]);
        *(bf16x8_t*)(&s_feat[k][grow*SFP + gc0]) = o.v8;
    }
    LIGHT_BARRIER();
    // ---- MFMA chunks 0..4 (slots 0..4)
    for (int k = 0; k < 5; k++) {
        bf16x8_t Bf[16];
        {
            int base = (wave*4*36 + k*4)*64 + lane;
            #pragma unroll
            for (int tl = 0; tl < 4; tl++)
                #pragma unroll
                for (int s4 = 0; s4 < 4; s4++)
                    Bf[tl*4 + s4] = Bp[base + (tl*36 + s4)*64];
        }
        const short* fb = s_feat[k];
        bf16x8_t av[4];
        #pragma unroll
        for (int s4 = 0; s4 < 4; s4++)
            av[s4] = *(const bf16x8_t*)(fb + arow*SFP + s4*32 + aq*8);
        #pragma unroll
        for (int tl = 0; tl < 4; tl++)
            #pragma unroll
            for (int s4 = 0; s4 < 4; s4++)
                acc[tl] = __builtin_amdgcn_mfma_f32_16x16x32_bf16(av[s4], Bf[tl*4 + s4], acc[tl], 0, 0, 0);
    }
    LIGHT_BARRIER();   // all waves done reading slots 0..3 before reuse
    // ---- round B: gather chunks 5..8 -> slots 0..3
    for (int k = 5; k < KK; k++) {
        float a0[8];
        #pragma unroll
        for (int j = 0; j < 8; j++) a0[j] = 0.0f;
        #pragma unroll
        for (int v = 0; v < 8; v++) {
            float w = wgt[v]; bf16x8_t d8 = tap[v];
            #pragma unroll
            for (int j = 0; j < 8; j++) a0[j] += w * b2f(d8[j]);
        }
        if (k < KK - 1) {
            const unsigned int* tp = &s_tap[((k+1)*MT + grow)*8];
            #pragma unroll
            for (int v = 0; v < 8; v++) {
                unsigned int e = tp[v];
                wgt[v] = __half2float(__ushort_as_half((unsigned short)(e & 0xffffu)));
                tap[v] = *(const bf16x8_t*)(xb + (size_t)(e >> 16) * CIN + gc0);
            }
        }
        union { bf16x8_t v8; __hip_bfloat16 hh[8]; } o;
        #pragma unroll
        for (int j = 0; j < 8; j++) o.hh[j] = __float2bfloat16(a0[j]);
        *(bf16x8_t*)(&s_feat[k-5][grow*SFP + gc0]) = o.v8;
    }
    LIGHT_BARRIER();
    // ---- MFMA chunks 5..8 (slots 0..3)
    for (int k = 5; k < KK; k++) {
        bf16x8_t Bf[16];
        {
            int base = (wave*4*36 + k*4)*64 + lane;
            #pragma unroll
            for (int tl = 0; tl < 4; tl++)
                #pragma unroll
                for (int s4 = 0; s4 < 4; s4++)
                    Bf[tl*4 + s4] = Bp[base + (tl*36 + s4)*64];
        }
        const short* fb = s_feat[k-5];
        bf16x8_t av[4];
        #pragma unroll
        for (int s4 = 0; s4 < 4; s4++)
            av[s4] = *(const bf16x8_t*)(fb + arow*SFP + s4*32 + aq*8);
        #pragma unroll
        for (int tl = 0; tl < 4; tl++)
            #pragma unroll
            for (int s4 = 0; s4 < 4; s4++)
                acc[tl] = __builtin_amdgcn_mfma_f32_16x16x32_bf16(av[s4], Bf[tl*4 + s4], acc[tl], 0, 0, 0);
    }

    // ---- epilogue
    #pragma unroll
    for (int tl = 0; tl < 4; tl++) {
        int n = (wave*4 + tl)*16 + arow;
        float bv = bu[n];
        f32x4_t vv;
        vv[0] = acc[tl][0] + bv;
        vv[1] = acc[tl][1] + bv;
        vv[2] = acc[tl][2] + bv;
        vv[3] = acc[tl][3] + bv;
        *(f32x4_t*)(out + ((size_t)b * COUT + n) * HW + ij0 + aq*4) = vv;
    }
}

// ---------------------------------------------------------------------------
extern "C" void kernel_launch(void* const* d_in, const int* in_sizes, int n_in,
                              void* d_out, int out_size, void* d_ws, size_t ws_size,
                              hipStream_t stream)
{
    const float* x   = (const float*)d_in[0];
    const float* W1  = (const float*)d_in[1];
    const float* b1  = (const float*)d_in[2];
    const float* W2  = (const float*)d_in[3];
    const float* b2  = (const float*)d_in[4];
    const float* Wu  = (const float*)d_in[5];
    const float* bu  = (const float*)d_in[6];
    const int* gints = (const int*)d_in[7];
    const int* roff  = (const int*)d_in[8];
    float* out = (float*)d_out;

    char* ws = (char*)d_ws;
    float* ws_means  = (float*)(ws + 0);                    // 2304*18 fp32
    float* ws_sigma  = (float*)(ws + 165888);               // 2304*9  fp32
    int*   ws_fl     = (int*  )(ws + 248832);               // 2304*18 int
    short* ws_xT     = (short*)(ws + 414720);               // 8*2304*128 bf16
    bf16x8_t* ws_bp  = (bf16x8_t*)(ws + 5133312);           // packed Wu bf16

    prep_kernel<<<1296, 256, 0, stream>>>(x, (__hip_bfloat16*)ws_xT, Wu, ws_bp,
                                          W1, b1, W2, b2,
                                          ws_means, ws_sigma, ws_fl);
    fused_kernel<<<MM/MT, 256, 0, stream>>>(ws_means, ws_sigma, ws_fl, gints, roff,
                                            ws_xT, ws_bp, bu, out);
}

// Round 18
// 144.423 us; speedup vs baseline: 1.2003x; 1.0025x over previous
//
#include <hip/hip_runtime.h>
#include <hip/hip_bf16.h>
#include <hip/hip_fp16.h>

// Problem constants
#define BB 8
#define CIN 128
#define HH 48
#define WW 48
#define HW 2304          // 48*48
#define KK 9
#define COUT 256
#define KC 1152          // K*CIN
#define MM 18432         // B*HW
#define MT 16            // M-tile rows per block
#define SFP 136          // feats LDS row stride in elements (16B-aligned)

// Barrier that waits only on LDS ops (ds_write visibility), leaving global
// loads in flight across the barrier.
#define LIGHT_BARRIER() asm volatile("s_waitcnt lgkmcnt(0)\n\ts_barrier" ::: "memory")

typedef short bf16x8_t __attribute__((ext_vector_type(8)));
typedef float f32x4_t  __attribute__((ext_vector_type(4)));

static __device__ __forceinline__ float b2f(short u) {
    union { unsigned int i; float f; } c;
    c.i = ((unsigned int)(unsigned short)u) << 16;
    return c.f;
}

// ---------------------------------------------------------------------------
// PREP kernel (R16 version, kept): transpose (0..575), pack_wu (576..719),
// params MLP in 3 groups of 9 (720..1295).
// ---------------------------------------------------------------------------
__global__ __launch_bounds__(256) void prep_kernel(
    const float* __restrict__ x, __hip_bfloat16* __restrict__ xT,
    const float* __restrict__ Wu, bf16x8_t* __restrict__ Bp,
    const float* __restrict__ W1, const float* __restrict__ b1,
    const float* __restrict__ W2, const float* __restrict__ b2,
    float* __restrict__ means, float* __restrict__ sigmas, int* __restrict__ fls)
{
    __shared__ double s_par[4][27];               // MLP group stash (864 B)
    int bid = blockIdx.x;
    int t = threadIdx.x;

    if (bid < 576) {
        __shared__ float tile[64][65];
        int ij0 = (bid % 36) * 64;
        int c0  = ((bid / 36) % 2) * 64;
        int b   = bid / 72;
        int ijl = t & 63, cl = t >> 6;
        #pragma unroll
        for (int i = 0; i < 16; i++) {
            int cc = i*4 + cl;
            tile[cc][ijl] = x[(size_t)(b*CIN + c0 + cc) * HW + ij0 + ijl];
        }
        __syncthreads();
        int cl2 = t & 63, ijl2 = t >> 6;
        #pragma unroll
        for (int i = 0; i < 16; i++) {
            int ij = i*4 + ijl2;
            xT[(size_t)(b*HW + ij0 + ij) * CIN + c0 + cl2] = __float2bfloat16(tile[cl2][ij]);
        }
    } else if (bid < 720) {
        int idx = (bid - 576) * 256 + t;          // 0 .. 36863
        int lane = idx & 63;
        int rest = idx >> 6;                      // 0 .. 575
        int ksub = rest % 36, tile16 = rest / 36;
        const float* src = Wu + (size_t)(tile16*16 + (lane & 15)) * KC
                              + ksub*32 + (lane >> 4)*8;
        union { bf16x8_t v; __hip_bfloat16 h[8]; } o;
        #pragma unroll
        for (int j = 0; j < 8; j++) o.h[j] = __float2bfloat16(src[j]);
        Bp[idx] = o.v;
    } else {
        int wave = t >> 6, lane = t & 63;
        int p = (bid - 720) * 4 + wave;           // 0..2303
        int iy = p / WW, ix = p % WW;
        float ryf = (float)iy / 47.0f;
        float rxf = (float)ix / 47.0f;
        double ry = (double)ryf, rx = (double)rxf;

        double h[8];
        #pragma unroll
        for (int jj = 0; jj < 8; jj++) {
            int j = lane*8 + jj;
            double v = ry * (double)W1[j*2+0] + rx * (double)W1[j*2+1] + (double)b1[j];
            h[jj] = v > 0.0 ? v : 0.0;
        }
        for (int g = 0; g < 3; g++) {
            double par[9];
            #pragma unroll
            for (int oo = 0; oo < 9; oo++) {
                int o = g*9 + oo;
                const float4* w4 = (const float4*)(W2 + (size_t)o*512 + lane*8);
                float4 wa = w4[0], wb = w4[1];
                double s = (double)wa.x*h[0] + (double)wa.y*h[1]
                         + (double)wa.z*h[2] + (double)wa.w*h[3]
                         + (double)wb.x*h[4] + (double)wb.y*h[5]
                         + (double)wb.z*h[6] + (double)wb.w*h[7];
                par[oo] = s;
            }
            #pragma unroll
            for (int oo = 0; oo < 9; oo++) {
                #pragma unroll
                for (int d = 1; d < 64; d <<= 1)
                    par[oo] += __shfl_xor(par[oo], d, 64);
            }
            if (lane == 0) {
                #pragma unroll
                for (int oo = 0; oo < 9; oo++)
                    s_par[wave][g*9 + oo] = par[oo] + (double)b2[g*9 + oo];
            }
        }
        __syncthreads();
        if (lane < KK) {
            int k = lane;
            double scy = ry * 0.9999 + 5e-05;
            double scx = rx * 0.9999 + 5e-05;
            double midy = log(scy / (1.0 - scy));
            double midx = log(scx / (1.0 - scx));
            double zy = midy + 0.1 * s_par[wave][2*k+0];
            double zx = midx + 0.1 * s_par[wave][2*k+1];
            double my = 47.0 / (1.0 + exp(-zy));
            double mx = 47.0 / (1.0 + exp(-zx));
            double sr = s_par[wave][18 + k] + 2.0;
            double sp = (sr > 0.0 ? sr : 0.0) + log1p(exp(-fabs(sr)));
            double sg = (sp + 0.05) * 48.0 * 0.05;
            means[(p*KK + k)*2 + 0] = (float)my;
            means[(p*KK + k)*2 + 1] = (float)mx;
            sigmas[p*KK + k] = (float)sg;
            fls[(p*KK + k)*2 + 0] = (int)floor(my);
            fls[(p*KK + k)*2 + 1] = (int)floor(mx);
        }
    }
}

// ---------------------------------------------------------------------------
// FUSED gather + GEMM (R19): R18's two-round/5-slot structure + explicit
// register double-buffering to break WAR serialization (R18: VGPR=64 = live
// set exactly -> prefetch reused consumer registers -> ~1 load in flight per
// wave; occupancy +32% moved nothing -> per-wave MLP is the limiter).
//   gather: tapA/wgtA vs tapB/wgtB alternate per chunk (straight-line).
//   mfma:   Bf split into halves; BfA=h0, BfB=h1; next chunk's h0 load
//           issues during h1's MFMAs. Same accumulation order per acc elem.
// Max live ~116 VGPR < 128 cap of (256,4): no spill expected.
// ---------------------------------------------------------------------------
#define TAP_LOAD(TP, WG, kk) do {                                             \
    const unsigned int* _tp = &s_tap[((kk)*MT + grow)*8];                     \
    _Pragma("unroll")                                                         \
    for (int v = 0; v < 8; v++) {                                             \
        unsigned int e = _tp[v];                                              \
        WG[v] = __half2float(__ushort_as_half((unsigned short)(e & 0xffffu)));\
        TP[v] = *(const bf16x8_t*)(xb + (size_t)(e >> 16) * CIN + gc0);       \
    } } while (0)

#define TAP_MATH(TP, WG, slot) do {                                           \
    float a0[8];                                                              \
    _Pragma("unroll") for (int j = 0; j < 8; j++) a0[j] = 0.0f;               \
    _Pragma("unroll")                                                         \
    for (int v = 0; v < 8; v++) {                                             \
        float w = WG[v]; bf16x8_t d8 = TP[v];                                 \
        _Pragma("unroll") for (int j = 0; j < 8; j++) a0[j] += w * b2f(d8[j]);\
    }                                                                         \
    union { bf16x8_t v8; __hip_bfloat16 hh[8]; } o;                           \
    _Pragma("unroll") for (int j = 0; j < 8; j++) o.hh[j] = __float2bfloat16(a0[j]); \
    *(bf16x8_t*)(&s_feat[slot][grow*SFP + gc0]) = o.v8;                       \
    } while (0)

#define BF_LOAD(BF, kk, hh) do {                                              \
    int _base = (wave*4*36 + (kk)*4)*64 + lane;                               \
    _Pragma("unroll")                                                         \
    for (int tl2 = 0; tl2 < 2; tl2++)                                         \
        _Pragma("unroll")                                                     \
        for (int s4 = 0; s4 < 4; s4++)                                        \
            BF[tl2*4 + s4] = Bp[_base + (((hh)*2 + tl2)*36 + s4)*64];         \
    } while (0)

#define HALF_MFMA(BF, hh) do {                                                \
    _Pragma("unroll")                                                         \
    for (int tl2 = 0; tl2 < 2; tl2++)                                         \
        _Pragma("unroll")                                                     \
        for (int s4 = 0; s4 < 4; s4++)                                        \
            acc[(hh)*2 + tl2] = __builtin_amdgcn_mfma_f32_16x16x32_bf16(      \
                av[s4], BF[tl2*4 + s4], acc[(hh)*2 + tl2], 0, 0, 0);          \
    } while (0)

#define AV_LOAD(slot) do {                                                    \
    const short* _fb = s_feat[slot];                                          \
    _Pragma("unroll")                                                         \
    for (int s4 = 0; s4 < 4; s4++)                                            \
        av[s4] = *(const bf16x8_t*)(_fb + arow*SFP + s4*32 + aq*8);           \
    } while (0)

__global__ __launch_bounds__(256, 4) void fused_kernel(
    const float* __restrict__ means, const float* __restrict__ sigmas,
    const int* __restrict__ fls, const int* __restrict__ gints,
    const int* __restrict__ roff, const short* __restrict__ xT,
    const bf16x8_t* __restrict__ Bp, const float* __restrict__ bu,
    float* __restrict__ out)
{
    __shared__ unsigned int s_tap[KK*MT*8];              // 4608 B
    __shared__ __align__(16) short s_feat[5][MT*SFP];    // 21760 B

    int t = threadIdx.x;
    int b   = blockIdx.x & 7;
    int grp = blockIdx.x >> 3;          // 0..143 within batch
    int ij0 = grp * MT;
    int m0  = b * HW + ij0;

    if (t < KK*MT) {                    // 144 threads
        int p = t;
        int k = p >> 4, row = p & 15;
        int ij = ij0 + row;
        int bij = m0 + row;
        int fy = fls[(ij*KK + k)*2 + 0];
        int fx = fls[(ij*KK + k)*2 + 1];
        float my = means[(ij*KK + k)*2 + 0];
        float mx = means[(ij*KK + k)*2 + 1];
        float sg = sigmas[ij*KK + k];
        int lins[8]; float ws[8];
        #pragma unroll
        for (int v = 0; v < 8; v++) {
            int iy, ix;
            if (v < 4) {
                iy = fy + (v >> 1); ix = fx + (v & 1);
            } else if (v < 6) {
                int base = ((bij*KK + k)*2 + (v - 4)) * 2;
                iy = gints[base]; ix = gints[base + 1];
            } else {
                int base = ((bij*KK + k)*2 + (v - 6)) * 2;
                iy = fy + roff[base] - 6; ix = fx + roff[base + 1] - 6;
            }
            iy = ((iy % HH) + HH) % HH;
            ix = ((ix % WW) + WW) % WW;
            lins[v] = iy * WW + ix;
            float dy = ((float)iy - my) / sg;
            float dx = ((float)ix - mx) / sg;
            ws[v] = expf(-0.5f * (dy*dy + dx*dx));
        }
        #pragma unroll
        for (int v = 1; v < 8; v++) {
            bool dup = false;
            #pragma unroll
            for (int u = 0; u < 8; u++) if (u < v) dup = dup || (lins[u] == lins[v]);
            if (dup) ws[v] = 0.0f;
        }
        float sum = 0.0f;
        #pragma unroll
        for (int v = 0; v < 8; v++) sum += ws[v];
        float inv = 1.0f / sum;
        #pragma unroll
        for (int v = 0; v < 8; v++) {
            unsigned short hb = __half_as_ushort(__float2half(ws[v] * inv));
            s_tap[p*8+v] = ((unsigned int)lins[v] << 16) | (unsigned int)hb;
        }
    }
    LIGHT_BARRIER();

    const short* xb = xT + (size_t)b * (HW * CIN);
    int lane = t & 63, wave = t >> 6;             // wave 0..3
    int grow = t >> 4, gc0 = (t & 15) << 3;       // gather: row (0..15), 8-ch base
    int arow = lane & 15, aq = lane >> 4;         // MFMA A/C lane decomposition

    f32x4_t acc[4] = {};                          // 4 col-tiles of 16
    bf16x8_t tapA[8], tapB[8];
    float    wgtA[8], wgtB[8];

    // ======== GATHER ROUND A: chunks 0..4 -> slots 0..4 (depth-2 pipeline)
    TAP_LOAD(tapA, wgtA, 0);
    TAP_LOAD(tapB, wgtB, 1);
    TAP_MATH(tapA, wgtA, 0);
    TAP_LOAD(tapA, wgtA, 2);
    TAP_MATH(tapB, wgtB, 1);
    TAP_LOAD(tapB, wgtB, 3);
    TAP_MATH(tapA, wgtA, 2);
    TAP_LOAD(tapA, wgtA, 4);
    TAP_MATH(tapB, wgtB, 3);
    TAP_MATH(tapA, wgtA, 4);
    LIGHT_BARRIER();

    // ======== MFMA ROUND A: chunks 0..4 (half-pipelined Bf)
    {
        bf16x8_t BfA[8], BfB[8], av[4];
        BF_LOAD(BfA, 0, 0);
        #pragma unroll
        for (int k = 0; k < 5; k++) {
            AV_LOAD(k);
            BF_LOAD(BfB, k, 1);
            HALF_MFMA(BfA, 0);
            if (k < 4) BF_LOAD(BfA, k+1, 0);
            HALF_MFMA(BfB, 1);
        }
    }
    LIGHT_BARRIER();   // all waves done reading slots 0..3 before reuse

    // ======== GATHER ROUND B: chunks 5..8 -> slots 0..3
    TAP_LOAD(tapB, wgtB, 5);
    TAP_LOAD(tapA, wgtA, 6);
    TAP_MATH(tapB, wgtB, 0);
    TAP_LOAD(tapB, wgtB, 7);
    TAP_MATH(tapA, wgtA, 1);
    TAP_LOAD(tapA, wgtA, 8);
    TAP_MATH(tapB, wgtB, 2);
    TAP_MATH(tapA, wgtA, 3);
    LIGHT_BARRIER();

    // ======== MFMA ROUND B: chunks 5..8 (slots 0..3)
    {
        bf16x8_t BfA[8], BfB[8], av[4];
        BF_LOAD(BfA, 5, 0);
        #pragma unroll
        for (int k = 5; k < KK; k++) {
            AV_LOAD(k-5);
            BF_LOAD(BfB, k, 1);
            HALF_MFMA(BfA, 0);
            if (k < KK-1) BF_LOAD(BfA, k+1, 0);
            HALF_MFMA(BfB, 1);
        }
    }

    // ---- epilogue
    #pragma unroll
    for (int tl = 0; tl < 4; tl++) {
        int n = (wave*4 + tl)*16 + arow;
        float bv = bu[n];
        f32x4_t vv;
        vv[0] = acc[tl][0] + bv;
        vv[1] = acc[tl][1] + bv;
        vv[2] = acc[tl][2] + bv;
        vv[3] = acc[tl][3] + bv;
        *(f32x4_t*)(out + ((size_t)b * COUT + n) * HW + ij0 + aq*4) = vv;
    }
}

// ---------------------------------------------------------------------------
extern "C" void kernel_launch(void* const* d_in, const int* in_sizes, int n_in,
                              void* d_out, int out_size, void* d_ws, size_t ws_size,
                              hipStream_t stream)
{
    const float* x   = (const float*)d_in[0];
    const float* W1  = (const float*)d_in[1];
    const float* b1  = (const float*)d_in[2];
    const float* W2  = (const float*)d_in[3];
    const float* b2  = (const float*)d_in[4];
    const float* Wu  = (const float*)d_in[5];
    const float* bu  = (const float*)d_in[6];
    const int* gints = (const int*)d_in[7];
    const int* roff  = (const int*)d_in[8];
    float* out = (float*)d_out;

    char* ws = (char*)d_ws;
    float* ws_means  = (float*)(ws + 0);                    // 2304*18 fp32
    float* ws_sigma  = (float*)(ws + 165888);               // 2304*9  fp32
    int*   ws_fl     = (int*  )(ws + 248832);               // 2304*18 int
    short* ws_xT     = (short*)(ws + 414720);               // 8*2304*128 bf16
    bf16x8_t* ws_bp  = (bf16x8_t*)(ws + 5133312);           // packed Wu bf16

    prep_kernel<<<1296, 256, 0, stream>>>(x, (__hip_bfloat16*)ws_xT, Wu, ws_bp,
                                          W1, b1, W2, b2,
                                          ws_means, ws_sigma, ws_fl);
    fused_kernel<<<MM/MT, 256, 0, stream>>>(ws_means, ws_sigma, ws_fl, gints, roff,
                                            ws_xT, ws_bp, bu, out);
}